// Round 1
// baseline (311.284 us; speedup 1.0000x reference)
//
#include <hip/hip_runtime.h>
#include <math.h>

// KAN attention: two spline-edge reductions (q,k branches) + bias + softmax(dim=8).
// batch=8, act_in=act_out=2048, C=8 spline coeffs/edge, N=4.19M edges/branch.
// Memory-bound: must stream coef_q/coef_k (268 MB) + mask/scale (67 MB).

#define ACT 2048
#define BATCH 8
#define OTILE 4
#define SPLITS 4
#define IBLK (ACT / SPLITS)   // 512
#define IPER (IBLK / 256)     // 2

__device__ __forceinline__ float dot4(const float4& a, const float4& b) {
  float r = a.x * b.x;
  r = fmaf(a.y, b.y, r);
  r = fmaf(a.z, b.z, r);
  r = fmaf(a.w, b.w, r);
  return r;
}

// ---------------------------------------------------------------------------
// Kernel 1: B-spline basis (Cox-de Boor, k=3, 12 uniform knots at -2.2+0.4j)
// and silu(x), for all (b,i) of both branches.
// Layout: B[i][b][c] (256 B per i, contiguous), base[i][b].
// ---------------------------------------------------------------------------
__global__ void kan_precompute(const float* __restrict__ q, const float* __restrict__ k,
                               float* __restrict__ Bq, float* __restrict__ Bk,
                               float* __restrict__ baseq, float* __restrict__ basek) {
  int tid = blockIdx.x * blockDim.x + threadIdx.x;
  if (tid >= ACT * BATCH) return;
  int i = tid >> 3;
  int b = tid & 7;
  const float t0 = -2.2f;
  const float h = 0.4f;
  for (int br = 0; br < 2; ++br) {
    const float* xsrc = br ? k : q;
    float* Bdst = br ? Bk : Bq;
    float* basedst = br ? basek : baseq;
    float x = xsrc[(size_t)b * ACT + i];
    float Bv[11];
#pragma unroll
    for (int j = 0; j < 11; ++j) {
      float tj = t0 + h * (float)j;
      float tj1 = t0 + h * (float)(j + 1);
      Bv[j] = (x >= tj && x < tj1) ? 1.0f : 0.0f;
    }
#pragma unroll
    for (int d = 1; d <= 3; ++d) {
      float inv = 1.0f / (h * (float)d);
#pragma unroll
      for (int j = 0; j + d < 11; ++j) {
        float tj = t0 + h * (float)j;
        float tjd1 = t0 + h * (float)(j + d + 1);
        Bv[j] = (x - tj) * inv * Bv[j] + (tjd1 - x) * inv * Bv[j + 1];
      }
    }
    float4* dst = reinterpret_cast<float4*>(Bdst + ((size_t)i * 8 + b) * 8);
    dst[0] = make_float4(Bv[0], Bv[1], Bv[2], Bv[3]);
    dst[1] = make_float4(Bv[4], Bv[5], Bv[6], Bv[7]);
    basedst[(size_t)i * 8 + b] = x / (1.0f + expf(-x));
  }
}

// ---------------------------------------------------------------------------
// Kernel 2: main reduction. Block = 256 threads, owns OTILE=4 outputs (o) and
// a 512-wide i chunk. Thread owns one i per iteration: 64 basis floats + 8
// silu values in registers (L2-resident), streams coef rows + mask/scales
// from HBM coalesced, accumulates acc[4][8]. Wave-shuffle reduce + atomicAdd.
// ---------------------------------------------------------------------------
__global__ __launch_bounds__(256) void kan_main(
    const float* __restrict__ coef_q, const float* __restrict__ coef_k,
    const float* __restrict__ scale_base, const float* __restrict__ scale_sp,
    const float* __restrict__ mask_q, const float* __restrict__ mask_k,
    const float* __restrict__ Bq, const float* __restrict__ Bk,
    const float* __restrict__ baseq, const float* __restrict__ basek,
    float* __restrict__ y) {
  const int t = threadIdx.x;
  const int ob = blockIdx.x / SPLITS;
  const int ic = blockIdx.x - ob * SPLITS;
  const int o0 = ob * OTILE;
  const int i0 = ic * IBLK;

  float acc[OTILE][BATCH];
#pragma unroll
  for (int os = 0; os < OTILE; ++os)
#pragma unroll
    for (int b = 0; b < BATCH; ++b) acc[os][b] = 0.0f;

  for (int br = 0; br < 2; ++br) {
    const float* __restrict__ coef = br ? coef_k : coef_q;
    const float* __restrict__ mask = br ? mask_k : mask_q;
    const float* __restrict__ Bws = br ? Bk : Bq;
    const float* __restrict__ bws = br ? basek : baseq;
#pragma unroll
    for (int j = 0; j < IPER; ++j) {
      const int i = i0 + j * 256 + t;
      const float4* Bp = reinterpret_cast<const float4*>(Bws + (size_t)i * 64);
      float4 Bv[16];
#pragma unroll
      for (int r = 0; r < 16; ++r) Bv[r] = Bp[r];
      const float4* bp = reinterpret_cast<const float4*>(bws + (size_t)i * 8);
      float4 bb0 = bp[0];
      float4 bb1 = bp[1];
      float bsv[8] = {bb0.x, bb0.y, bb0.z, bb0.w, bb1.x, bb1.y, bb1.z, bb1.w};
#pragma unroll
      for (int os = 0; os < OTILE; ++os) {
        const size_t e = (((size_t)(o0 + os)) << 11) + (size_t)i;
        const float4* cp = reinterpret_cast<const float4*>(coef + e * 8);
        float4 c0 = cp[0];
        float4 c1 = cp[1];
        float m = mask[e];
        float vb = scale_base[e] * m;
        float vs = scale_sp[e] * m;
#pragma unroll
        for (int b = 0; b < BATCH; ++b) {
          float d = dot4(Bv[2 * b], c0) + dot4(Bv[2 * b + 1], c1);
          float a = acc[os][b];
          a = fmaf(vs, d, a);
          a = fmaf(vb, bsv[b], a);
          acc[os][b] = a;
        }
      }
    }
  }

#pragma unroll
  for (int os = 0; os < OTILE; ++os) {
#pragma unroll
    for (int b = 0; b < BATCH; ++b) {
      float v = acc[os][b];
#pragma unroll
      for (int off = 32; off > 0; off >>= 1) v += __shfl_down(v, off);
      if ((t & 63) == 0) atomicAdd(&y[(size_t)b * ACT + (size_t)(o0 + os)], v);
    }
  }
}

// ---------------------------------------------------------------------------
// Kernel 3: bias + softmax over trailing dim of 8. One thread per row of 8.
// ---------------------------------------------------------------------------
__global__ void kan_softmax(const float* __restrict__ y, const float* __restrict__ bias,
                            float* __restrict__ out) {
  int g = blockIdx.x * blockDim.x + threadIdx.x;
  if (g >= BATCH * ACT / 8) return;
  int b = g >> 8;
  int grp = g & 255;
  const float* yp = y + (size_t)b * ACT + (size_t)grp * 8;
  const float* bp = bias + (size_t)grp * 8;
  float4 y0 = reinterpret_cast<const float4*>(yp)[0];
  float4 y1 = reinterpret_cast<const float4*>(yp)[1];
  float4 w0 = reinterpret_cast<const float4*>(bp)[0];
  float4 w1 = reinterpret_cast<const float4*>(bp)[1];
  float v[8] = {y0.x + w0.x, y0.y + w0.y, y0.z + w0.z, y0.w + w0.w,
                y1.x + w1.x, y1.y + w1.y, y1.z + w1.z, y1.w + w1.w};
  float mx = v[0];
#pragma unroll
  for (int j = 1; j < 8; ++j) mx = fmaxf(mx, v[j]);
  float s = 0.0f;
#pragma unroll
  for (int j = 0; j < 8; ++j) {
    v[j] = expf(v[j] - mx);
    s += v[j];
  }
  float inv = 1.0f / s;
  float* op = out + (size_t)b * ACT + (size_t)grp * 8;
  reinterpret_cast<float4*>(op)[0] = make_float4(v[0] * inv, v[1] * inv, v[2] * inv, v[3] * inv);
  reinterpret_cast<float4*>(op)[1] = make_float4(v[4] * inv, v[5] * inv, v[6] * inv, v[7] * inv);
}

// ---------------------------------------------------------------------------
// Workspace layout (floats):
//   y      @ 0        : 16384   (zeroed each call; atomicAdd target)
//   Bq     @ 16384    : 131072  ([i][b][c])
//   Bk     @ 147456   : 131072
//   baseq  @ 278528   : 16384   ([i][b])
//   basek  @ 294912   : 16384
// total 311296 floats = 1.19 MiB
// ---------------------------------------------------------------------------
extern "C" void kernel_launch(void* const* d_in, const int* in_sizes, int n_in,
                              void* d_out, int out_size, void* d_ws, size_t ws_size,
                              hipStream_t stream) {
  const float* q          = (const float*)d_in[0];
  const float* k          = (const float*)d_in[1];
  const float* coef_q     = (const float*)d_in[2];
  const float* coef_k     = (const float*)d_in[3];
  const float* scale_base = (const float*)d_in[4];
  const float* scale_sp   = (const float*)d_in[5];
  const float* mask_q     = (const float*)d_in[6];
  const float* mask_k     = (const float*)d_in[7];
  const float* bias_w     = (const float*)d_in[8];
  float* out = (float*)d_out;

  float* ws    = (float*)d_ws;
  float* y     = ws;
  float* Bq    = ws + 16384;
  float* Bk    = Bq + 131072;
  float* baseq = Bk + 131072;
  float* basek = baseq + 16384;

  hipMemsetAsync(y, 0, 16384 * sizeof(float), stream);
  kan_precompute<<<dim3(64), dim3(256), 0, stream>>>(q, k, Bq, Bk, baseq, basek);
  kan_main<<<dim3((ACT / OTILE) * SPLITS), dim3(256), 0, stream>>>(
      coef_q, coef_k, scale_base, scale_sp, mask_q, mask_k, Bq, Bk, baseq, basek, y);
  kan_softmax<<<dim3(8), dim3(256), 0, stream>>>(y, bias_w, out);
}

// Round 2
// 186.911 us; speedup vs baseline: 1.6654x; 1.6654x over previous
//
#include <hip/hip_runtime.h>
#include <math.h>

// KAN attention: two spline-edge reductions (q,k branches) + bias + softmax(dim=8).
// batch=8, act_in=act_out=2048, C=8 spline coeffs/edge, N=4.19M edges/branch.
// Memory-bound: streams coef_q/coef_k (268 MB) + mask/scale (~100 MB).
//
// R1 -> R2: previous version was latency-bound (occupancy 11%, VGPR 132,
// serial per-os load rounds, 520 GB/s). Now: B/base staged in LDS (freeing
// 64 VGPRs), all 20 global loads of a branch issued up front, B reused across
// 4 outputs from LDS. Target: HBM-bound ~60-90 us.

#define ACT 2048
#define BATCH 8
#define IBLK 128              // i per block
#define NIC (ACT / IBLK)      // 16 i-chunks
#define OTILE 8               // o per block (4 per thread-half)
#define NOC (ACT / OTILE)     // 256 o-chunks

__device__ __forceinline__ float dot4(const float4& a, const float4& b) {
  float r = a.x * b.x;
  r = fmaf(a.y, b.y, r);
  r = fmaf(a.z, b.z, r);
  r = fmaf(a.w, b.w, r);
  return r;
}

// ---------------------------------------------------------------------------
// Kernel 1: B-spline basis (Cox-de Boor, k=3, 12 uniform knots at -2.2+0.4j)
// and silu(x) for all (b,i) of both branches.
// Output layout (chunk-transposed for coalesced LDS staging + reads):
//   B[ic][b][h][il]  as float4   (ic=i/128, h=coef half, il=i%128)
//   base[ic][b][il]  as float
// ---------------------------------------------------------------------------
__global__ void kan_precompute(const float* __restrict__ q, const float* __restrict__ k,
                               float4* __restrict__ Bq, float4* __restrict__ Bk,
                               float* __restrict__ baseq, float* __restrict__ basek) {
  int tid = blockIdx.x * blockDim.x + threadIdx.x;
  if (tid >= ACT * BATCH) return;
  int il = tid & (IBLK - 1);
  int b = (tid >> 7) & 7;
  int ic = tid >> 10;
  int i = ic * IBLK + il;
  const float t0 = -2.2f;
  const float h = 0.4f;
  for (int br = 0; br < 2; ++br) {
    const float* xsrc = br ? k : q;
    float4* Bdst = br ? Bk : Bq;
    float* basedst = br ? basek : baseq;
    float x = xsrc[(size_t)b * ACT + i];
    float Bv[11];
#pragma unroll
    for (int j = 0; j < 11; ++j) {
      float tj = t0 + h * (float)j;
      float tj1 = t0 + h * (float)(j + 1);
      Bv[j] = (x >= tj && x < tj1) ? 1.0f : 0.0f;
    }
#pragma unroll
    for (int d = 1; d <= 3; ++d) {
      float inv = 1.0f / (h * (float)d);
#pragma unroll
      for (int j = 0; j + d < 11; ++j) {
        float tj = t0 + h * (float)j;
        float tjd1 = t0 + h * (float)(j + d + 1);
        Bv[j] = (x - tj) * inv * Bv[j] + (tjd1 - x) * inv * Bv[j + 1];
      }
    }
    Bdst[((size_t)ic * 16 + b * 2 + 0) * IBLK + il] = make_float4(Bv[0], Bv[1], Bv[2], Bv[3]);
    Bdst[((size_t)ic * 16 + b * 2 + 1) * IBLK + il] = make_float4(Bv[4], Bv[5], Bv[6], Bv[7]);
    basedst[((size_t)ic * 8 + b) * IBLK + il] = x / (1.0f + expf(-x));
  }
}

// ---------------------------------------------------------------------------
// Kernel 2: main reduction. Block = 256 threads = 4 waves; tile = 128 i x 8 o.
// Thread: i = t&127, owns 4 consecutive o. Per branch: stage B(32KB)+base(4KB)
// chunk into LDS (coalesced, conflict-free contiguous reads), issue all coef/
// mask/scale loads up front, then b-loop reuses LDS B across the 4 outputs.
// Wave-shuffle reduce over the 64-lane i-dim + atomicAdd into y.
// ---------------------------------------------------------------------------
__global__ __launch_bounds__(256) void kan_main(
    const float* __restrict__ coef_q, const float* __restrict__ coef_k,
    const float* __restrict__ scale_base, const float* __restrict__ scale_sp,
    const float* __restrict__ mask_q, const float* __restrict__ mask_k,
    const float4* __restrict__ Bq, const float4* __restrict__ Bk,
    const float* __restrict__ baseq, const float* __restrict__ basek,
    float* __restrict__ y) {
  __shared__ float4 Bs[16 * IBLK];     // [(b*2+h)][il]
  __shared__ float bases[8 * IBLK];    // [b][il]

  const int t = threadIdx.x;
  const int ob = blockIdx.x / NIC;
  const int ic = blockIdx.x - ob * NIC;
  const int o0 = ob * OTILE;
  const int i0 = ic * IBLK;
  const int i = t & (IBLK - 1);
  const int og = t >> 7;               // 0 or 1: which 4 outputs

  float acc[4][BATCH];
#pragma unroll
  for (int os = 0; os < 4; ++os)
#pragma unroll
    for (int b = 0; b < BATCH; ++b) acc[os][b] = 0.0f;

  for (int br = 0; br < 2; ++br) {
    const float* __restrict__ coef = br ? coef_k : coef_q;
    const float* __restrict__ mask = br ? mask_k : mask_q;
    const float4* __restrict__ Bsrc = (br ? Bk : Bq) + (size_t)ic * 16 * IBLK;
    const float4* __restrict__ bsrc =
        reinterpret_cast<const float4*>((br ? basek : baseq) + (size_t)ic * 8 * IBLK);

    if (br) __syncthreads();           // previous branch done reading LDS
#pragma unroll
    for (int r = 0; r < 8; ++r) Bs[r * 256 + t] = Bsrc[r * 256 + t];
    reinterpret_cast<float4*>(bases)[t] = bsrc[t];
    __syncthreads();

    // Issue all global loads for this branch up front (independent).
    float4 c[4][2];
    float vb[4], vs[4];
#pragma unroll
    for (int os = 0; os < 4; ++os) {
      const size_t e = ((size_t)(o0 + og * 4 + os)) * ACT + (size_t)(i0 + i);
      const float4* cp = reinterpret_cast<const float4*>(coef + e * 8);
      c[os][0] = cp[0];
      c[os][1] = cp[1];
      float m = mask[e];
      vb[os] = scale_base[e] * m;
      vs[os] = scale_sp[e] * m;
    }

#pragma unroll
    for (int b = 0; b < BATCH; ++b) {
      float4 B0 = Bs[(b * 2 + 0) * IBLK + i];
      float4 B1 = Bs[(b * 2 + 1) * IBLK + i];
      float bas = bases[b * IBLK + i];
#pragma unroll
      for (int os = 0; os < 4; ++os) {
        float d = dot4(B0, c[os][0]) + dot4(B1, c[os][1]);
        acc[os][b] = fmaf(vs[os], d, fmaf(vb[os], bas, acc[os][b]));
      }
    }
  }

#pragma unroll
  for (int os = 0; os < 4; ++os) {
#pragma unroll
    for (int b = 0; b < BATCH; ++b) {
      float v = acc[os][b];
#pragma unroll
      for (int off = 32; off > 0; off >>= 1) v += __shfl_down(v, off);
      if ((t & 63) == 0)
        atomicAdd(&y[(size_t)b * ACT + (size_t)(o0 + og * 4 + os)], v);
    }
  }
}

// ---------------------------------------------------------------------------
// Kernel 3: bias + softmax over trailing dim of 8. One thread per row of 8.
// ---------------------------------------------------------------------------
__global__ void kan_softmax(const float* __restrict__ y, const float* __restrict__ bias,
                            float* __restrict__ out) {
  int g = blockIdx.x * blockDim.x + threadIdx.x;
  if (g >= BATCH * ACT / 8) return;
  int b = g >> 8;
  int grp = g & 255;
  const float* yp = y + (size_t)b * ACT + (size_t)grp * 8;
  const float* bp = bias + (size_t)grp * 8;
  float4 y0 = reinterpret_cast<const float4*>(yp)[0];
  float4 y1 = reinterpret_cast<const float4*>(yp)[1];
  float4 w0 = reinterpret_cast<const float4*>(bp)[0];
  float4 w1 = reinterpret_cast<const float4*>(bp)[1];
  float v[8] = {y0.x + w0.x, y0.y + w0.y, y0.z + w0.z, y0.w + w0.w,
                y1.x + w1.x, y1.y + w1.y, y1.z + w1.z, y1.w + w1.w};
  float mx = v[0];
#pragma unroll
  for (int j = 1; j < 8; ++j) mx = fmaxf(mx, v[j]);
  float s = 0.0f;
#pragma unroll
  for (int j = 0; j < 8; ++j) {
    v[j] = expf(v[j] - mx);
    s += v[j];
  }
  float inv = 1.0f / s;
  float* op = out + (size_t)b * ACT + (size_t)grp * 8;
  reinterpret_cast<float4*>(op)[0] = make_float4(v[0] * inv, v[1] * inv, v[2] * inv, v[3] * inv);
  reinterpret_cast<float4*>(op)[1] = make_float4(v[4] * inv, v[5] * inv, v[6] * inv, v[7] * inv);
}

// ---------------------------------------------------------------------------
// Workspace layout (floats):
//   y      @ 0        : 16384   (zeroed each call; atomicAdd target)
//   Bq     @ 16384    : 131072  ([ic][b][h][il] float4)
//   Bk     @ 147456   : 131072
//   baseq  @ 278528   : 16384   ([ic][b][il])
//   basek  @ 294912   : 16384
// total 311296 floats = 1.19 MiB
// ---------------------------------------------------------------------------
extern "C" void kernel_launch(void* const* d_in, const int* in_sizes, int n_in,
                              void* d_out, int out_size, void* d_ws, size_t ws_size,
                              hipStream_t stream) {
  const float* q          = (const float*)d_in[0];
  const float* k          = (const float*)d_in[1];
  const float* coef_q     = (const float*)d_in[2];
  const float* coef_k     = (const float*)d_in[3];
  const float* scale_base = (const float*)d_in[4];
  const float* scale_sp   = (const float*)d_in[5];
  const float* mask_q     = (const float*)d_in[6];
  const float* mask_k     = (const float*)d_in[7];
  const float* bias_w     = (const float*)d_in[8];
  float* out = (float*)d_out;

  float* ws    = (float*)d_ws;
  float* y     = ws;
  float* Bq    = ws + 16384;
  float* Bk    = Bq + 131072;
  float* baseq = Bk + 131072;
  float* basek = baseq + 16384;

  hipMemsetAsync(y, 0, 16384 * sizeof(float), stream);
  kan_precompute<<<dim3(64), dim3(256), 0, stream>>>(
      q, k, (float4*)Bq, (float4*)Bk, baseq, basek);
  kan_main<<<dim3(NOC * NIC), dim3(256), 0, stream>>>(
      coef_q, coef_k, scale_base, scale_sp, mask_q, mask_k,
      (const float4*)Bq, (const float4*)Bk, baseq, basek, y);
  kan_softmax<<<dim3(8), dim3(256), 0, stream>>>(y, bias_w, out);
}